// Round 9
// baseline (67.065 us; speedup 1.0000x reference)
//
#include <hip/hip_runtime.h>
#include <hip/hip_bf16.h>

#define BB 16
#define NN 16384
#define DD 128
#define CC 32
#define CHUNKS 32
#define NBLK (BB * CHUNKS)                  // 512
#define ROWS_PER_BLOCK (NN / CHUNKS)        // 512
#define ROWS_PER_WAVE  (ROWS_PER_BLOCK / 4) // 128

// ---- PATH A workspace layout (floats) ----
#define P_SUMS 0                                    // NBLK*4096
#define P_CNTS ((size_t)NBLK * CC * DD)             // NBLK*32
#define R_SUMS (P_CNTS + (size_t)NBLK * CC)         // BB*4096
#define R_CNTS (R_SUMS + (size_t)BB * CC * DD)      // BB*32
#define LOSSP  (R_CNTS + (size_t)BB * CC)           // BB
#define BCTR   (LOSSP + BB)                         // BB ints
#define GCTR   (BCTR + BB)                          // 1 int
#define WS_A_FLOATS (GCTR + 1)

// ---------------- Kernel 1: segment sums + counts (branchless LDS RMW) ------
// Proven engine (R4-R7, bit-exact): 512 blocks, 4 waves, per-wave 16 KB slab,
// plain ds_read_b64 + 2 adds + ds_write_b64; 16 loads in flight. PATH A
// epilogue: fold 4 slabs, plain-store partial to own slot; block 0 resets the
// finish counters (stream order makes this visible to finish2).
__global__ __launch_bounds__(256) void seg_sum_kernel(
    const float* __restrict__ x, const int* __restrict__ ids,
    float* __restrict__ outsums, float* __restrict__ outcnts,
    int* __restrict__ bctr, int* __restrict__ gctr) {
  __shared__ float lsum[4][CC * DD];      // 64 KB
  __shared__ float lcnt[CC];
  __shared__ int   lcid[ROWS_PER_BLOCK];  // 2 KB

  const int tid  = threadIdx.x;
  const int b    = blockIdx.y;
  const int row0 = blockIdx.x * ROWS_PER_BLOCK;
  const int lane = tid & 63;
  const int w    = tid >> 6;
  const int slot = b * CHUNKS + blockIdx.x;
  const int* __restrict__ idrow = ids + (size_t)b * NN;

  if (tid < CC) lcnt[tid] = 0.f;
  lcid[tid]       = idrow[row0 + tid];
  lcid[tid + 256] = idrow[row0 + tid + 256];
  {
    const float4 z4 = make_float4(0.f, 0.f, 0.f, 0.f);
#pragma unroll
    for (int i = 0; i < 16; ++i)
      *reinterpret_cast<float4*>(&lsum[w][(i * 64 + lane) * 4]) = z4;
  }
  __syncthreads();
  atomicAdd(&lcnt[lcid[tid]], 1.f);
  atomicAdd(&lcnt[lcid[tid + 256]], 1.f);

  const float2* __restrict__ x2 =
      reinterpret_cast<const float2*>(x + (size_t)b * NN * DD);
  const int wbase = w * ROWS_PER_WAVE;
  float* const slab = &lsum[w][0];

  float2 vA[16], vB[16];
  int cA[16], cB[16];

#define LOADG(V, C, g)                                                     \
  {                                                                        \
    _Pragma("unroll") for (int k = 0; k < 16; ++k) {                       \
      const int rl = wbase + (g) * 16 + k;                                 \
      V[k] = x2[(size_t)(row0 + rl) * 64 + lane];                          \
      C[k] = lcid[rl];                                                     \
    }                                                                      \
  }
#define RMWG(V, C)                                                         \
  {                                                                        \
    _Pragma("unroll") for (int k = 0; k < 16; ++k) {                       \
      float2* p = reinterpret_cast<float2*>(&slab[C[k] * DD + 2 * lane]);  \
      float2 old = *p;                                                     \
      *p = make_float2(old.x + V[k].x, old.y + V[k].y);                    \
    }                                                                      \
  }

  LOADG(vA, cA, 0)                         // 8 groups of 16 rows
#pragma unroll
  for (int i = 0; i < 3; ++i) {
    LOADG(vB, cB, 2 * i + 1)
    RMWG(vA, cA)
    LOADG(vA, cA, 2 * i + 2)
    RMWG(vB, cB)
  }
  LOADG(vB, cB, 7)
  RMWG(vA, cA)
  RMWG(vB, cB)
#undef LOADG
#undef RMWG
  __syncthreads();

  float* __restrict__ ps = outsums + (size_t)slot * CC * DD;
#pragma unroll
  for (int it = 0; it < 4; ++it) {
    const int i = (it * 256 + tid) * 4;
    float4 s0 = *reinterpret_cast<const float4*>(&lsum[0][i]);
    float4 s1 = *reinterpret_cast<const float4*>(&lsum[1][i]);
    float4 s2 = *reinterpret_cast<const float4*>(&lsum[2][i]);
    float4 s3 = *reinterpret_cast<const float4*>(&lsum[3][i]);
    float4 r = make_float4(s0.x + s1.x + s2.x + s3.x, s0.y + s1.y + s2.y + s3.y,
                           s0.z + s1.z + s2.z + s3.z, s0.w + s1.w + s2.w + s3.w);
    *reinterpret_cast<float4*>(&ps[i]) = r;
  }
  if (tid < CC) outcnts[slot * CC + tid] = lcnt[tid];
  if (slot == 0) {
    if (tid < BB)
      __hip_atomic_store(&bctr[tid], 0, __ATOMIC_RELAXED, __HIP_MEMORY_SCOPE_AGENT);
    if (tid == BB)
      __hip_atomic_store(gctr, 0, __ATOMIC_RELAXED, __HIP_MEMORY_SCOPE_AGENT);
  }
}

// ---------------- Kernel 2: parallel reduce + per-batch gram + final --------
// 256 blocks x 256 thr. Block j=(b,p): reduces elements [p*256,p*256+256) of
// batch b across 32 slabs (full-chip parallel). The 16th-arriving block of a
// batch (device counter) runs that batch's gram from L2-hot rsums; the 16th
// batch-finisher sums lossp in fixed order -> out. Fully deterministic.
#define MSTR 132
__global__ __launch_bounds__(256) void finish2_kernel(
    const float* __restrict__ psums, const float* __restrict__ pcnts,
    float* __restrict__ rsums, float* __restrict__ rcnts,
    float* __restrict__ lossp, int* __restrict__ bctr, int* __restrict__ gctr,
    float* __restrict__ out) {
  __shared__ float mean[CC * MSTR];  // 16.9 KB
  __shared__ float cnt[CC];
  __shared__ float red[256];
  __shared__ int   lastF;

  const int j = blockIdx.x;
  const int b = j >> 4;
  const int p = j & 15;
  const int tid = threadIdx.x;

  // --- phase 1: slab reduce (coalesced; thread t owns one element) ---
  {
    const int e = p * 256 + tid;
    const float* base = psums + (size_t)b * CHUNKS * CC * DD + e;
    float s = 0.f;
#pragma unroll 8
    for (int c = 0; c < CHUNKS; ++c) s += base[(size_t)c * CC * DD];
    rsums[(size_t)b * CC * DD + e] = s;
  }
  if (p == 0 && tid < CC) {
    float cs = 0.f;
#pragma unroll 8
    for (int c = 0; c < CHUNKS; ++c) cs += pcnts[(b * CHUNKS + c) * CC + tid];
    rcnts[b * CC + tid] = cs;
  }
  __threadfence();
  __syncthreads();
  if (tid == 0) {
    int old = __hip_atomic_fetch_add(&bctr[b], 1, __ATOMIC_ACQ_REL,
                                     __HIP_MEMORY_SCOPE_AGENT);
    lastF = (old == 15);
  }
  __syncthreads();
  if (!lastF) return;
  __threadfence();  // acquire: rsums/rcnts from the other 15 blocks

  // --- phase 2: gram for batch b (one block) ---
  if (tid < CC) cnt[tid] = rcnts[b * CC + tid];
  __syncthreads();
  for (int i = tid; i < CC * DD; i += 256) {
    int c = i >> 7;
    int d = i & 127;
    mean[c * MSTR + d] = rsums[(size_t)b * CC * DD + i] / fmaxf(cnt[c], 1.f);
  }
  __syncthreads();

  float acc = 0.f;
  for (int pp = tid; pp < (CC * (CC - 1)) / 2; pp += 256) {
    int c = 0, rem = pp;
    while (rem >= (CC - 1 - c)) { rem -= (CC - 1 - c); ++c; }
    int e = c + 1 + rem;
    const float4* mc = reinterpret_cast<const float4*>(&mean[c * MSTR]);
    const float4* me = reinterpret_cast<const float4*>(&mean[e * MSTR]);
    float dot = 0.f;
#pragma unroll 8
    for (int jj = 0; jj < DD / 4; ++jj) {
      float4 u = mc[jj], v = me[jj];
      dot += u.x * v.x + u.y * v.y + u.z * v.z + u.w * v.w;
    }
    acc += fabsf(dot);
  }
  red[tid] = acc;
  __syncthreads();
  for (int s = 128; s > 0; s >>= 1) {
    if (tid < s) red[tid] += red[tid + s];
    __syncthreads();
  }

  if (tid == 0) {
    float valid = 0.f;
    for (int c = 0; c < CC; ++c) valid += (cnt[c] > 0.f) ? 1.f : 0.f;
    float denom = (valid > 1.f) ? valid * (valid - 1.f) * 0.5f : 1.f;
    float v = red[0] / denom * (1.0f / BB);
    __hip_atomic_store(&lossp[b], v, __ATOMIC_RELAXED, __HIP_MEMORY_SCOPE_AGENT);
    __threadfence();
    int old = __hip_atomic_fetch_add(gctr, 1, __ATOMIC_ACQ_REL,
                                     __HIP_MEMORY_SCOPE_AGENT);
    if (old == BB - 1) {
      __threadfence();
      float s = 0.f;
#pragma unroll
      for (int i = 0; i < BB; ++i)
        s += __hip_atomic_load(&lossp[i], __ATOMIC_RELAXED,
                               __HIP_MEMORY_SCOPE_AGENT);
      out[0] = s;
    }
  }
}

// ---------------- PATH B fallback (atomic accumulate) -----------------------
__global__ __launch_bounds__(256) void seg_sum_rmw_b(
    const float* __restrict__ x, const int* __restrict__ ids,
    float* __restrict__ gsums, float* __restrict__ gcounts) {
  __shared__ float lsum[4][CC * DD];
  __shared__ float lcnt[CC];
  __shared__ int   lcid[ROWS_PER_BLOCK];

  const int tid  = threadIdx.x;
  const int b    = blockIdx.y;
  const int row0 = blockIdx.x * ROWS_PER_BLOCK;
  const int lane = tid & 63;
  const int w    = tid >> 6;
  const int* __restrict__ idrow = ids + (size_t)b * NN;

  if (tid < CC) lcnt[tid] = 0.f;
  lcid[tid]       = idrow[row0 + tid];
  lcid[tid + 256] = idrow[row0 + tid + 256];
  {
    const float4 z4 = make_float4(0.f, 0.f, 0.f, 0.f);
#pragma unroll
    for (int i = 0; i < 16; ++i)
      *reinterpret_cast<float4*>(&lsum[w][(i * 64 + lane) * 4]) = z4;
  }
  __syncthreads();
  atomicAdd(&lcnt[lcid[tid]], 1.f);
  atomicAdd(&lcnt[lcid[tid + 256]], 1.f);

  const float2* __restrict__ x2 =
      reinterpret_cast<const float2*>(x + (size_t)b * NN * DD);
  const int wbase = w * ROWS_PER_WAVE;
  float* const slab = &lsum[w][0];

  for (int g = 0; g < ROWS_PER_WAVE / 8; ++g) {
    float2 v[8]; int cid[8];
#pragma unroll
    for (int k = 0; k < 8; ++k) {
      const int rl = wbase + g * 8 + k;
      v[k]   = x2[(size_t)(row0 + rl) * 64 + lane];
      cid[k] = lcid[rl];
    }
#pragma unroll
    for (int k = 0; k < 8; ++k) {
      float2* p = reinterpret_cast<float2*>(&slab[cid[k] * DD + 2 * lane]);
      float2 old = *p;
      *p = make_float2(old.x + v[k].x, old.y + v[k].y);
    }
  }
  __syncthreads();

  float* __restrict__ gs = gsums + (size_t)b * CC * DD;
  for (int i = tid; i < CC * DD; i += 256) {
    float s = lsum[0][i] + lsum[1][i] + lsum[2][i] + lsum[3][i];
    atomicAdd(&gs[i], s);
  }
  if (tid < CC) atomicAdd(&gcounts[b * CC + tid], lcnt[tid]);
}

__global__ __launch_bounds__(512) void finish_kernel_b(
    const float* __restrict__ gsums, const float* __restrict__ gcounts,
    float* __restrict__ out) {
  __shared__ float mean[CC * MSTR];
  __shared__ float cnt[CC];
  __shared__ float red[512];

  const int b = blockIdx.x;
  const int tid = threadIdx.x;

  if (tid < CC) cnt[tid] = gcounts[b * CC + tid];
  __syncthreads();
  for (int i = tid; i < CC * DD; i += 512) {
    int c = i >> 7;
    int d = i & 127;
    mean[c * MSTR + d] = gsums[(size_t)b * CC * DD + i] / fmaxf(cnt[c], 1.f);
  }
  __syncthreads();

  float acc = 0.f;
  if (tid < (CC * (CC - 1)) / 2) {
    int c = 0, rem = tid;
    while (rem >= (CC - 1 - c)) { rem -= (CC - 1 - c); ++c; }
    int e = c + 1 + rem;
    const float4* mc = reinterpret_cast<const float4*>(&mean[c * MSTR]);
    const float4* me = reinterpret_cast<const float4*>(&mean[e * MSTR]);
    float dot = 0.f;
#pragma unroll 8
    for (int jj = 0; jj < DD / 4; ++jj) {
      float4 u = mc[jj], v = me[jj];
      dot += u.x * v.x + u.y * v.y + u.z * v.z + u.w * v.w;
    }
    acc = fabsf(dot);
  }
  red[tid] = acc;
  __syncthreads();
  for (int s = 256; s > 0; s >>= 1) {
    if (tid < s) red[tid] += red[tid + s];
    __syncthreads();
  }
  if (tid == 0) {
    float valid = 0.f;
    for (int c = 0; c < CC; ++c) valid += (cnt[c] > 0.f) ? 1.f : 0.f;
    float denom = (valid > 1.f) ? valid * (valid - 1.f) * 0.5f : 1.f;
    atomicAdd(out, red[0] / denom * (1.0f / BB));
  }
}

extern "C" void kernel_launch(void* const* d_in, const int* in_sizes, int n_in,
                              void* d_out, int out_size, void* d_ws, size_t ws_size,
                              hipStream_t stream) {
  const float* x   = (const float*)d_in[0];
  const int*   ids = (const int*)d_in[1];
  float* out = (float*)d_out;
  float* ws  = (float*)d_ws;

  dim3 grid1(CHUNKS, BB);
  if (ws_size >= WS_A_FLOATS * sizeof(float)) {
    float* psums = ws + P_SUMS;
    float* pcnts = ws + P_CNTS;
    float* rsums = ws + R_SUMS;
    float* rcnts = ws + R_CNTS;
    float* lossp = ws + LOSSP;
    int*   bctr  = (int*)(ws + BCTR);
    int*   gctr  = (int*)(ws + GCTR);
    seg_sum_kernel<<<grid1, 256, 0, stream>>>(x, ids, psums, pcnts, bctr, gctr);
    finish2_kernel<<<NBLK / 2, 256, 0, stream>>>(psums, pcnts, rsums, rcnts,
                                                 lossp, bctr, gctr, out);
  } else {
    float* gsums   = ws;
    float* gcounts = gsums + (size_t)BB * CC * DD;
    const size_t wsb = ((size_t)BB * CC * DD + (size_t)BB * CC) * sizeof(float);
    hipMemsetAsync(d_ws, 0, wsb, stream);
    hipMemsetAsync(d_out, 0, sizeof(float), stream);
    seg_sum_rmw_b<<<grid1, 256, 0, stream>>>(x, ids, gsums, gcounts);
    finish_kernel_b<<<BB, 512, 0, stream>>>(gsums, gcounts, out);
  }
}

// Round 10
// 40.507 us; speedup vs baseline: 1.6557x; 1.6557x over previous
//
#include <hip/hip_runtime.h>
#include <hip/hip_bf16.h>

#define BB 16
#define NN 16384
#define DD 128
#define CC 32
#define CHUNKS 32
#define NBLK (BB * CHUNKS)                  // 512
#define ROWS_PER_BLOCK (NN / CHUNKS)        // 512
#define ROWS_PER_WAVE  (ROWS_PER_BLOCK / 4) // 128

// ---- PATH A workspace layout (floats) ----
#define P_SUMS 0                                    // NBLK*4096
#define P_CNTS ((size_t)NBLK * CC * DD)             // NBLK*32
#define R_SUMS (P_CNTS + (size_t)NBLK * CC)         // BB*4096
#define R_CNTS (R_SUMS + (size_t)BB * CC * DD)      // BB*32
#define LOSSP  (R_CNTS + (size_t)BB * CC)           // BB
#define GCTR   (LOSSP + BB)                         // 1 int
#define WS_A_FLOATS (GCTR + 1)

// ---------------- Kernel 1: segment sums + counts (branchless LDS RMW) ------
// Proven engine (R4-R7, bit-exact). 512 blocks, 4 waves, per-wave 16 KB slab;
// plain ds_read_b64 + 2 adds + ds_write_b64; 16 loads in flight. Epilogue:
// fold 4 slabs, plain-store partial to own slot; slot 0 resets gctr (stream
// order makes it visible to finish16 two launches later).
__global__ __launch_bounds__(256) void seg_sum_kernel(
    const float* __restrict__ x, const int* __restrict__ ids,
    float* __restrict__ outsums, float* __restrict__ outcnts,
    int* __restrict__ gctr) {
  __shared__ float lsum[4][CC * DD];      // 64 KB
  __shared__ float lcnt[CC];
  __shared__ int   lcid[ROWS_PER_BLOCK];  // 2 KB

  const int tid  = threadIdx.x;
  const int b    = blockIdx.y;
  const int row0 = blockIdx.x * ROWS_PER_BLOCK;
  const int lane = tid & 63;
  const int w    = tid >> 6;
  const int slot = b * CHUNKS + blockIdx.x;
  const int* __restrict__ idrow = ids + (size_t)b * NN;

  if (tid < CC) lcnt[tid] = 0.f;
  lcid[tid]       = idrow[row0 + tid];
  lcid[tid + 256] = idrow[row0 + tid + 256];
  {
    const float4 z4 = make_float4(0.f, 0.f, 0.f, 0.f);
#pragma unroll
    for (int i = 0; i < 16; ++i)
      *reinterpret_cast<float4*>(&lsum[w][(i * 64 + lane) * 4]) = z4;
  }
  __syncthreads();
  atomicAdd(&lcnt[lcid[tid]], 1.f);
  atomicAdd(&lcnt[lcid[tid + 256]], 1.f);

  const float2* __restrict__ x2 =
      reinterpret_cast<const float2*>(x + (size_t)b * NN * DD);
  const int wbase = w * ROWS_PER_WAVE;
  float* const slab = &lsum[w][0];

  float2 vA[16], vB[16];
  int cA[16], cB[16];

#define LOADG(V, C, g)                                                     \
  {                                                                        \
    _Pragma("unroll") for (int k = 0; k < 16; ++k) {                       \
      const int rl = wbase + (g) * 16 + k;                                 \
      V[k] = x2[(size_t)(row0 + rl) * 64 + lane];                          \
      C[k] = lcid[rl];                                                     \
    }                                                                      \
  }
#define RMWG(V, C)                                                         \
  {                                                                        \
    _Pragma("unroll") for (int k = 0; k < 16; ++k) {                       \
      float2* p = reinterpret_cast<float2*>(&slab[C[k] * DD + 2 * lane]);  \
      float2 old = *p;                                                     \
      *p = make_float2(old.x + V[k].x, old.y + V[k].y);                    \
    }                                                                      \
  }

  LOADG(vA, cA, 0)                         // 8 groups of 16 rows
#pragma unroll
  for (int i = 0; i < 3; ++i) {
    LOADG(vB, cB, 2 * i + 1)
    RMWG(vA, cA)
    LOADG(vA, cA, 2 * i + 2)
    RMWG(vB, cB)
  }
  LOADG(vB, cB, 7)
  RMWG(vA, cA)
  RMWG(vB, cB)
#undef LOADG
#undef RMWG
  __syncthreads();

  float* __restrict__ ps = outsums + (size_t)slot * CC * DD;
#pragma unroll
  for (int it = 0; it < 4; ++it) {
    const int i = (it * 256 + tid) * 4;
    float4 s0 = *reinterpret_cast<const float4*>(&lsum[0][i]);
    float4 s1 = *reinterpret_cast<const float4*>(&lsum[1][i]);
    float4 s2 = *reinterpret_cast<const float4*>(&lsum[2][i]);
    float4 s3 = *reinterpret_cast<const float4*>(&lsum[3][i]);
    float4 r = make_float4(s0.x + s1.x + s2.x + s3.x, s0.y + s1.y + s2.y + s3.y,
                           s0.z + s1.z + s2.z + s3.z, s0.w + s1.w + s2.w + s3.w);
    *reinterpret_cast<float4*>(&ps[i]) = r;
  }
  if (tid < CC) outcnts[slot * CC + tid] = lcnt[tid];
  if (slot == 0 && tid == 0)
    __hip_atomic_store(gctr, 0, __ATOMIC_RELAXED, __HIP_MEMORY_SCOPE_AGENT);
}

// ---------------- Kernel 2: full-chip fold of 32 partials per batch ---------
// 256 blocks x 256 thr: thread owns ONE element of one batch (65536 total).
// 8.4 MB read spread over 256 CUs (~2 us) instead of 16 CUs (R7's tail).
__global__ __launch_bounds__(256) void reduce_partials_kernel(
    const float* __restrict__ psums, const float* __restrict__ pcnts,
    float* __restrict__ rsums, float* __restrict__ rcnts) {
  const int j = blockIdx.x;
  const int b = j >> 4;
  const int e = (j & 15) * 256 + threadIdx.x;
  const float* base = psums + (size_t)b * CHUNKS * CC * DD + e;
  float s = 0.f;
#pragma unroll 8
  for (int c = 0; c < CHUNKS; ++c) s += base[(size_t)c * CC * DD];
  rsums[(size_t)b * CC * DD + e] = s;
  if ((j & 15) == 0 && threadIdx.x < CC) {
    float cs = 0.f;
#pragma unroll 8
    for (int c = 0; c < CHUNKS; ++c)
      cs += pcnts[(b * CHUNKS + c) * CC + threadIdx.x];
    rcnts[b * CC + threadIdx.x] = cs;
  }
}

// ---------------- Kernel 3: gram + triu + counter-based final ---------------
// 16 blocks x 512 thr reading L2-hot rsums (16 KB/block). Counter pattern
// proven in R7/R8 (kernel-boundary visibility; no fences in hot path).
#define MSTR 132
__global__ __launch_bounds__(512) void finish16_kernel(
    const float* __restrict__ rsums, const float* __restrict__ rcnts,
    float* __restrict__ lossp, int* __restrict__ gctr,
    float* __restrict__ out) {
  __shared__ float mean[CC * MSTR];
  __shared__ float cnt[CC];
  __shared__ float red[512];

  const int b = blockIdx.x;
  const int tid = threadIdx.x;

  if (tid < CC) cnt[tid] = rcnts[b * CC + tid];
  __syncthreads();

  for (int i = tid; i < CC * DD; i += 512) {
    int c = i >> 7;
    int d = i & 127;
    mean[c * MSTR + d] = rsums[(size_t)b * CC * DD + i] / fmaxf(cnt[c], 1.f);
  }
  __syncthreads();

  float acc = 0.f;
  if (tid < (CC * (CC - 1)) / 2) {
    int c = 0, rem = tid;
    while (rem >= (CC - 1 - c)) { rem -= (CC - 1 - c); ++c; }
    int e = c + 1 + rem;
    const float4* mc = reinterpret_cast<const float4*>(&mean[c * MSTR]);
    const float4* me = reinterpret_cast<const float4*>(&mean[e * MSTR]);
    float dot = 0.f;
#pragma unroll 8
    for (int jj = 0; jj < DD / 4; ++jj) {
      float4 u = mc[jj], v = me[jj];
      dot += u.x * v.x + u.y * v.y + u.z * v.z + u.w * v.w;
    }
    acc = fabsf(dot);
  }
  red[tid] = acc;
  __syncthreads();
  for (int s = 256; s > 0; s >>= 1) {
    if (tid < s) red[tid] += red[tid + s];
    __syncthreads();
  }

  if (tid == 0) {
    float valid = 0.f;
    for (int c = 0; c < CC; ++c) valid += (cnt[c] > 0.f) ? 1.f : 0.f;
    float denom = (valid > 1.f) ? valid * (valid - 1.f) * 0.5f : 1.f;
    float v = red[0] / denom * (1.0f / BB);
    __hip_atomic_store(&lossp[b], v, __ATOMIC_RELAXED, __HIP_MEMORY_SCOPE_AGENT);
    __threadfence();
    int old = __hip_atomic_fetch_add(gctr, 1, __ATOMIC_ACQ_REL,
                                     __HIP_MEMORY_SCOPE_AGENT);
    if (old == BB - 1) {
      __threadfence();
      float s = 0.f;
#pragma unroll
      for (int i = 0; i < BB; ++i)
        s += __hip_atomic_load(&lossp[i], __ATOMIC_RELAXED,
                               __HIP_MEMORY_SCOPE_AGENT);
      out[0] = s;
    }
  }
}

// ---------------- PATH B fallback (atomic accumulate) -----------------------
__global__ __launch_bounds__(256) void seg_sum_rmw_b(
    const float* __restrict__ x, const int* __restrict__ ids,
    float* __restrict__ gsums, float* __restrict__ gcounts) {
  __shared__ float lsum[4][CC * DD];
  __shared__ float lcnt[CC];
  __shared__ int   lcid[ROWS_PER_BLOCK];

  const int tid  = threadIdx.x;
  const int b    = blockIdx.y;
  const int row0 = blockIdx.x * ROWS_PER_BLOCK;
  const int lane = tid & 63;
  const int w    = tid >> 6;
  const int* __restrict__ idrow = ids + (size_t)b * NN;

  if (tid < CC) lcnt[tid] = 0.f;
  lcid[tid]       = idrow[row0 + tid];
  lcid[tid + 256] = idrow[row0 + tid + 256];
  {
    const float4 z4 = make_float4(0.f, 0.f, 0.f, 0.f);
#pragma unroll
    for (int i = 0; i < 16; ++i)
      *reinterpret_cast<float4*>(&lsum[w][(i * 64 + lane) * 4]) = z4;
  }
  __syncthreads();
  atomicAdd(&lcnt[lcid[tid]], 1.f);
  atomicAdd(&lcnt[lcid[tid + 256]], 1.f);

  const float2* __restrict__ x2 =
      reinterpret_cast<const float2*>(x + (size_t)b * NN * DD);
  const int wbase = w * ROWS_PER_WAVE;
  float* const slab = &lsum[w][0];

  for (int g = 0; g < ROWS_PER_WAVE / 8; ++g) {
    float2 v[8]; int cid[8];
#pragma unroll
    for (int k = 0; k < 8; ++k) {
      const int rl = wbase + g * 8 + k;
      v[k]   = x2[(size_t)(row0 + rl) * 64 + lane];
      cid[k] = lcid[rl];
    }
#pragma unroll
    for (int k = 0; k < 8; ++k) {
      float2* p = reinterpret_cast<float2*>(&slab[cid[k] * DD + 2 * lane]);
      float2 old = *p;
      *p = make_float2(old.x + v[k].x, old.y + v[k].y);
    }
  }
  __syncthreads();

  float* __restrict__ gs = gsums + (size_t)b * CC * DD;
  for (int i = tid; i < CC * DD; i += 256) {
    float s = lsum[0][i] + lsum[1][i] + lsum[2][i] + lsum[3][i];
    atomicAdd(&gs[i], s);
  }
  if (tid < CC) atomicAdd(&gcounts[b * CC + tid], lcnt[tid]);
}

__global__ __launch_bounds__(512) void finish_kernel_b(
    const float* __restrict__ gsums, const float* __restrict__ gcounts,
    float* __restrict__ out) {
  __shared__ float mean[CC * MSTR];
  __shared__ float cnt[CC];
  __shared__ float red[512];

  const int b = blockIdx.x;
  const int tid = threadIdx.x;

  if (tid < CC) cnt[tid] = gcounts[b * CC + tid];
  __syncthreads();
  for (int i = tid; i < CC * DD; i += 512) {
    int c = i >> 7;
    int d = i & 127;
    mean[c * MSTR + d] = gsums[(size_t)b * CC * DD + i] / fmaxf(cnt[c], 1.f);
  }
  __syncthreads();

  float acc = 0.f;
  if (tid < (CC * (CC - 1)) / 2) {
    int c = 0, rem = tid;
    while (rem >= (CC - 1 - c)) { rem -= (CC - 1 - c); ++c; }
    int e = c + 1 + rem;
    const float4* mc = reinterpret_cast<const float4*>(&mean[c * MSTR]);
    const float4* me = reinterpret_cast<const float4*>(&mean[e * MSTR]);
    float dot = 0.f;
#pragma unroll 8
    for (int jj = 0; jj < DD / 4; ++jj) {
      float4 u = mc[jj], v = me[jj];
      dot += u.x * v.x + u.y * v.y + u.z * v.z + u.w * v.w;
    }
    acc = fabsf(dot);
  }
  red[tid] = acc;
  __syncthreads();
  for (int s = 256; s > 0; s >>= 1) {
    if (tid < s) red[tid] += red[tid + s];
    __syncthreads();
  }
  if (tid == 0) {
    float valid = 0.f;
    for (int c = 0; c < CC; ++c) valid += (cnt[c] > 0.f) ? 1.f : 0.f;
    float denom = (valid > 1.f) ? valid * (valid - 1.f) * 0.5f : 1.f;
    atomicAdd(out, red[0] / denom * (1.0f / BB));
  }
}

extern "C" void kernel_launch(void* const* d_in, const int* in_sizes, int n_in,
                              void* d_out, int out_size, void* d_ws, size_t ws_size,
                              hipStream_t stream) {
  const float* x   = (const float*)d_in[0];
  const int*   ids = (const int*)d_in[1];
  float* out = (float*)d_out;
  float* ws  = (float*)d_ws;

  dim3 grid1(CHUNKS, BB);
  if (ws_size >= WS_A_FLOATS * sizeof(float)) {
    float* psums = ws + P_SUMS;
    float* pcnts = ws + P_CNTS;
    float* rsums = ws + R_SUMS;
    float* rcnts = ws + R_CNTS;
    float* lossp = ws + LOSSP;
    int*   gctr  = (int*)(ws + GCTR);
    seg_sum_kernel<<<grid1, 256, 0, stream>>>(x, ids, psums, pcnts, gctr);
    reduce_partials_kernel<<<256, 256, 0, stream>>>(psums, pcnts, rsums, rcnts);
    finish16_kernel<<<BB, 512, 0, stream>>>(rsums, rcnts, lossp, gctr, out);
  } else {
    float* gsums   = ws;
    float* gcounts = gsums + (size_t)BB * CC * DD;
    const size_t wsb = ((size_t)BB * CC * DD + (size_t)BB * CC) * sizeof(float);
    hipMemsetAsync(d_ws, 0, wsb, stream);
    hipMemsetAsync(d_out, 0, sizeof(float), stream);
    seg_sum_rmw_b<<<grid1, 256, 0, stream>>>(x, ids, gsums, gcounts);
    finish_kernel_b<<<BB, 512, 0, stream>>>(gsums, gcounts, out);
  }
}

// Round 11
// 39.350 us; speedup vs baseline: 1.7043x; 1.0294x over previous
//
#include <hip/hip_runtime.h>
#include <hip/hip_bf16.h>

#define BB 16
#define NN 16384
#define DD 128
#define CC 32
#define CHUNKS 32
#define NBLK (BB * CHUNKS)                  // 512
#define ROWS_PER_BLOCK (NN / CHUNKS)        // 512

// ---- PATH A workspace layout (floats) ----
#define P_SUMS 0                                    // NBLK*4096
#define P_CNTS ((size_t)NBLK * CC * DD)             // NBLK*32
#define LOSSP  (P_CNTS + (size_t)NBLK * CC)         // BB
#define GCTR   (LOSSP + BB)                         // 1 int
#define WS_A_FLOATS (GCTR + 1)

// ---------------- Kernel 1: segment sums (col-split, 16 waves/CU) -----------
// 512 blocks x 512 thr (8 waves). Wave w=(rr,h): rows [rr*128, rr*128+128),
// cols [h*64, h*64+64); per-wave slab = 32 clusters x 64 cols = 8 KB (vs 16 KB
// full-row slabs in R4-R10). LDS/block = 66 KB -> 2 blocks/CU but now
// 16 waves/CU (4/SIMD) instead of 8 — doubles VMEM-issue duty when waves
// alternate load-burst/DS-burst (H-lat theory). Scalar f32 loads (R8 showed
// width irrelevant). Accumulation order per column identical to R7 -> bitexact.
__global__ __launch_bounds__(512, 4) void seg_sum_kernel(
    const float* __restrict__ x, const int* __restrict__ ids,
    float* __restrict__ outsums, float* __restrict__ outcnts,
    int* __restrict__ gctr) {
  __shared__ float slab[8][CC * 64];      // 8 x 8 KB = 64 KB
  __shared__ float lcnt[CC];
  __shared__ int   lcid[ROWS_PER_BLOCK];  // 2 KB

  const int tid  = threadIdx.x;
  const int b    = blockIdx.y;
  const int row0 = blockIdx.x * ROWS_PER_BLOCK;
  const int lane = tid & 63;
  const int w    = tid >> 6;              // wave 0..7
  const int rr   = w >> 1;                // row-quarter 0..3
  const int h    = w & 1;                 // col-half 0..1
  const int slot = b * CHUNKS + blockIdx.x;
  const int* __restrict__ idrow = ids + (size_t)b * NN;

  if (tid < CC) lcnt[tid] = 0.f;
  lcid[tid] = idrow[row0 + tid];          // 512 thr, 1 row each
  {
    const float4 z4 = make_float4(0.f, 0.f, 0.f, 0.f);
#pragma unroll
    for (int i = 0; i < 8; ++i)           // 8*64*4 floats = 2048 = slab size
      *reinterpret_cast<float4*>(&slab[w][(i * 64 + lane) * 4]) = z4;
  }
  __syncthreads();
  atomicAdd(&lcnt[lcid[tid]], 1.f);

  // lane's column: h*64 + lane... lane in 0..63 covers the 64-col half.
  const float* __restrict__ p0 =
      x + ((size_t)b * NN + row0 + rr * 128) * DD + h * 64 + lane;
  const int kb0 = rr * 128;
  float* const sl = &slab[w][0];

  float vA[8], vB[8];
  int cA[8], cB[8];

#define LOADG(V, C, g)                                                     \
  {                                                                        \
    _Pragma("unroll") for (int k = 0; k < 8; ++k) {                        \
      V[k] = p0[((g) * 8 + k) * DD];                                       \
      C[k] = lcid[kb0 + (g) * 8 + k];                                      \
    }                                                                      \
  }
#define RMWG(V, C)                                                         \
  {                                                                        \
    _Pragma("unroll") for (int k = 0; k < 8; ++k) {                        \
      float* p = &sl[C[k] * 64 + lane];                                    \
      *p = *p + V[k];                                                      \
    }                                                                      \
  }

  LOADG(vA, cA, 0)                        // 16 groups of 8 rows, ping-pong
#pragma unroll
  for (int i = 0; i < 7; ++i) {
    LOADG(vB, cB, 2 * i + 1)
    RMWG(vA, cA)
    LOADG(vA, cA, 2 * i + 2)
    RMWG(vB, cB)
  }
  LOADG(vB, cB, 15)
  RMWG(vA, cA)                            // group 14
  RMWG(vB, cB)                            // group 15
#undef LOADG
#undef RMWG
  __syncthreads();

  // epilogue: fold 4 row-quarters per col-half, plain-store 16 KB partial
  float* __restrict__ ps = outsums + (size_t)slot * CC * DD;
#pragma unroll
  for (int it = 0; it < 8; ++it) {
    const int idx = it * 512 + tid;       // 0..4095 = c*128 + h2*64 + j
    const int c  = idx >> 7;
    const int r  = idx & 127;
    const int h2 = r >> 6;
    const int j  = r & 63;
    const int o  = c * 64 + j;
    ps[idx] = slab[h2][o] + slab[2 + h2][o] + slab[4 + h2][o] + slab[6 + h2][o];
  }
  if (tid < CC) outcnts[slot * CC + tid] = lcnt[tid];
  if (slot == 0 && tid == 0)
    __hip_atomic_store(gctr, 0, __ATOMIC_RELAXED, __HIP_MEMORY_SCOPE_AGENT);
}

// ---------------- Kernel 2: fused reduce + gram + final (R7, proven) --------
#define MSTR 132
__global__ __launch_bounds__(512) void finish_fused_kernel(
    const float* __restrict__ psums, const float* __restrict__ pcnts,
    float* __restrict__ lossp, int* __restrict__ gctr,
    float* __restrict__ out) {
  __shared__ float mean[CC * MSTR];
  __shared__ float cnt[CC];
  __shared__ float red[512];

  const int b = blockIdx.x;
  const int tid = threadIdx.x;

  if (tid < CC) {
    float cs = 0.f;
#pragma unroll 8
    for (int c = 0; c < CHUNKS; ++c) cs += pcnts[(b * CHUNKS + c) * CC + tid];
    cnt[tid] = cs;
  }

  float4 a0 = make_float4(0.f, 0.f, 0.f, 0.f), a1 = a0;
  const size_t base = (size_t)b * CHUNKS * CC * DD + (size_t)tid * 8;
#pragma unroll 4
  for (int c = 0; c < CHUNKS; ++c) {
    const float4* p = reinterpret_cast<const float4*>(&psums[base + (size_t)c * CC * DD]);
    float4 q0 = p[0], q1 = p[1];
    a0.x += q0.x; a0.y += q0.y; a0.z += q0.z; a0.w += q0.w;
    a1.x += q1.x; a1.y += q1.y; a1.z += q1.z; a1.w += q1.w;
  }
  __syncthreads();

  {
    const int c = tid >> 4;
    const int d0 = (tid & 15) * 8;
    const float inv = 1.f / fmaxf(cnt[c], 1.f);
    float* mrow = &mean[c * MSTR + d0];
    mrow[0] = a0.x * inv; mrow[1] = a0.y * inv; mrow[2] = a0.z * inv; mrow[3] = a0.w * inv;
    mrow[4] = a1.x * inv; mrow[5] = a1.y * inv; mrow[6] = a1.z * inv; mrow[7] = a1.w * inv;
  }
  __syncthreads();

  float acc = 0.f;
  if (tid < (CC * (CC - 1)) / 2) {
    int c = 0, rem = tid;
    while (rem >= (CC - 1 - c)) { rem -= (CC - 1 - c); ++c; }
    int e = c + 1 + rem;
    const float4* mc = reinterpret_cast<const float4*>(&mean[c * MSTR]);
    const float4* me = reinterpret_cast<const float4*>(&mean[e * MSTR]);
    float dot = 0.f;
#pragma unroll 8
    for (int j = 0; j < DD / 4; ++j) {
      float4 u = mc[j], v = me[j];
      dot += u.x * v.x + u.y * v.y + u.z * v.z + u.w * v.w;
    }
    acc = fabsf(dot);
  }

  red[tid] = acc;
  __syncthreads();
  for (int s = 256; s > 0; s >>= 1) {
    if (tid < s) red[tid] += red[tid + s];
    __syncthreads();
  }

  if (tid == 0) {
    float valid = 0.f;
    for (int c = 0; c < CC; ++c) valid += (cnt[c] > 0.f) ? 1.f : 0.f;
    float denom = (valid > 1.f) ? valid * (valid - 1.f) * 0.5f : 1.f;
    float v = red[0] / denom * (1.0f / BB);
    __hip_atomic_store(&lossp[b], v, __ATOMIC_RELAXED, __HIP_MEMORY_SCOPE_AGENT);
    __threadfence();
    int old = __hip_atomic_fetch_add(gctr, 1, __ATOMIC_ACQ_REL,
                                     __HIP_MEMORY_SCOPE_AGENT);
    if (old == BB - 1) {
      __threadfence();
      float s = 0.f;
#pragma unroll
      for (int i = 0; i < BB; ++i)
        s += __hip_atomic_load(&lossp[i], __ATOMIC_RELAXED,
                               __HIP_MEMORY_SCOPE_AGENT);
      out[0] = s;
    }
  }
}

// ---------------- PATH B fallback (atomic accumulate) -----------------------
#define ROWS_PER_WAVE_B 128
__global__ __launch_bounds__(256) void seg_sum_rmw_b(
    const float* __restrict__ x, const int* __restrict__ ids,
    float* __restrict__ gsums, float* __restrict__ gcounts) {
  __shared__ float lsum[4][CC * DD];
  __shared__ float lcnt[CC];
  __shared__ int   lcid[ROWS_PER_BLOCK];

  const int tid  = threadIdx.x;
  const int b    = blockIdx.y;
  const int row0 = blockIdx.x * ROWS_PER_BLOCK;
  const int lane = tid & 63;
  const int w    = tid >> 6;
  const int* __restrict__ idrow = ids + (size_t)b * NN;

  if (tid < CC) lcnt[tid] = 0.f;
  lcid[tid]       = idrow[row0 + tid];
  lcid[tid + 256] = idrow[row0 + tid + 256];
  {
    const float4 z4 = make_float4(0.f, 0.f, 0.f, 0.f);
#pragma unroll
    for (int i = 0; i < 16; ++i)
      *reinterpret_cast<float4*>(&lsum[w][(i * 64 + lane) * 4]) = z4;
  }
  __syncthreads();
  atomicAdd(&lcnt[lcid[tid]], 1.f);
  atomicAdd(&lcnt[lcid[tid + 256]], 1.f);

  const float2* __restrict__ x2 =
      reinterpret_cast<const float2*>(x + (size_t)b * NN * DD);
  const int wbase = w * ROWS_PER_WAVE_B;
  float* const slab = &lsum[w][0];

  for (int g = 0; g < ROWS_PER_WAVE_B / 8; ++g) {
    float2 v[8]; int cid[8];
#pragma unroll
    for (int k = 0; k < 8; ++k) {
      const int rl = wbase + g * 8 + k;
      v[k]   = x2[(size_t)(row0 + rl) * 64 + lane];
      cid[k] = lcid[rl];
    }
#pragma unroll
    for (int k = 0; k < 8; ++k) {
      float2* p = reinterpret_cast<float2*>(&slab[cid[k] * DD + 2 * lane]);
      float2 old = *p;
      *p = make_float2(old.x + v[k].x, old.y + v[k].y);
    }
  }
  __syncthreads();

  float* __restrict__ gs = gsums + (size_t)b * CC * DD;
  for (int i = tid; i < CC * DD; i += 256) {
    float s = lsum[0][i] + lsum[1][i] + lsum[2][i] + lsum[3][i];
    atomicAdd(&gs[i], s);
  }
  if (tid < CC) atomicAdd(&gcounts[b * CC + tid], lcnt[tid]);
}

__global__ __launch_bounds__(512) void finish_kernel_b(
    const float* __restrict__ gsums, const float* __restrict__ gcounts,
    float* __restrict__ out) {
  __shared__ float mean[CC * MSTR];
  __shared__ float cnt[CC];
  __shared__ float red[512];

  const int b = blockIdx.x;
  const int tid = threadIdx.x;

  if (tid < CC) cnt[tid] = gcounts[b * CC + tid];
  __syncthreads();
  for (int i = tid; i < CC * DD; i += 512) {
    int c = i >> 7;
    int d = i & 127;
    mean[c * MSTR + d] = gsums[(size_t)b * CC * DD + i] / fmaxf(cnt[c], 1.f);
  }
  __syncthreads();

  float acc = 0.f;
  if (tid < (CC * (CC - 1)) / 2) {
    int c = 0, rem = tid;
    while (rem >= (CC - 1 - c)) { rem -= (CC - 1 - c); ++c; }
    int e = c + 1 + rem;
    const float4* mc = reinterpret_cast<const float4*>(&mean[c * MSTR]);
    const float4* me = reinterpret_cast<const float4*>(&mean[e * MSTR]);
    float dot = 0.f;
#pragma unroll 8
    for (int jj = 0; jj < DD / 4; ++jj) {
      float4 u = mc[jj], v = me[jj];
      dot += u.x * v.x + u.y * v.y + u.z * v.z + u.w * v.w;
    }
    acc = fabsf(dot);
  }
  red[tid] = acc;
  __syncthreads();
  for (int s = 256; s > 0; s >>= 1) {
    if (tid < s) red[tid] += red[tid + s];
    __syncthreads();
  }
  if (tid == 0) {
    float valid = 0.f;
    for (int c = 0; c < CC; ++c) valid += (cnt[c] > 0.f) ? 1.f : 0.f;
    float denom = (valid > 1.f) ? valid * (valid - 1.f) * 0.5f : 1.f;
    atomicAdd(out, red[0] / denom * (1.0f / BB));
  }
}

extern "C" void kernel_launch(void* const* d_in, const int* in_sizes, int n_in,
                              void* d_out, int out_size, void* d_ws, size_t ws_size,
                              hipStream_t stream) {
  const float* x   = (const float*)d_in[0];
  const int*   ids = (const int*)d_in[1];
  float* out = (float*)d_out;
  float* ws  = (float*)d_ws;

  dim3 grid1(CHUNKS, BB);
  if (ws_size >= WS_A_FLOATS * sizeof(float)) {
    float* psums = ws + P_SUMS;
    float* pcnts = ws + P_CNTS;
    float* lossp = ws + LOSSP;
    int*   gctr  = (int*)(ws + GCTR);
    seg_sum_kernel<<<grid1, 512, 0, stream>>>(x, ids, psums, pcnts, gctr);
    finish_fused_kernel<<<BB, 512, 0, stream>>>(psums, pcnts, lossp, gctr, out);
  } else {
    float* gsums   = ws;
    float* gcounts = gsums + (size_t)BB * CC * DD;
    const size_t wsb = ((size_t)BB * CC * DD + (size_t)BB * CC) * sizeof(float);
    hipMemsetAsync(d_ws, 0, wsb, stream);
    hipMemsetAsync(d_out, 0, sizeof(float), stream);
    seg_sum_rmw_b<<<grid1, 256, 0, stream>>>(x, ids, gsums, gcounts);
    finish_kernel_b<<<BB, 512, 0, stream>>>(gsums, gcounts, out);
  }
}

// Round 12
// 38.074 us; speedup vs baseline: 1.7614x; 1.0335x over previous
//
#include <hip/hip_runtime.h>
#include <hip/hip_bf16.h>

#define BB 16
#define NN 16384
#define DD 128
#define CC 32
#define CHUNKS 16
#define NBLK (BB * CHUNKS)                  // 256
#define ROWS_PER_BLOCK (NN / CHUNKS)        // 1024

// ---- PATH A workspace layout (floats) ----
#define P_SUMS 0                                    // NBLK*4096 (4.2 MB)
#define P_CNTS ((size_t)NBLK * CC * DD)             // NBLK*32
#define LOSSP  (P_CNTS + (size_t)NBLK * CC)         // BB
#define GCTR   (LOSSP + BB)                         // 1 int
#define WS_A_FLOATS (GCTR + 1)

// ---------------- Kernel 1: segment sums (col-split engine, nt loads) -------
// 256 blocks x 512 thr (8 waves = 4 row-quarters x 2 col-halves). Per-wave
// slab = 32x64 = 8 KB; LDS 68 KB -> 2 blocks/CU. Engine identical to R11
// (ties with all other engines) except: CHUNKS 32->16 (halves psums traffic
// + tail read) and __builtin_nontemporal_load on x (bypass L1 retention —
// tests the L1-fill-path ceiling theory; x has zero reuse inside a call).
__global__ __launch_bounds__(512) void seg_sum_kernel(
    const float* __restrict__ x, const int* __restrict__ ids,
    float* __restrict__ outsums, float* __restrict__ outcnts,
    int* __restrict__ gctr) {
  __shared__ float slab[8][CC * 64];      // 64 KB
  __shared__ float lcnt[CC];
  __shared__ int   lcid[ROWS_PER_BLOCK];  // 4 KB

  const int tid  = threadIdx.x;
  const int b    = blockIdx.y;
  const int row0 = blockIdx.x * ROWS_PER_BLOCK;
  const int lane = tid & 63;
  const int w    = tid >> 6;              // wave 0..7
  const int rr   = w >> 1;                // row-quarter 0..3 (256 rows each)
  const int h    = w & 1;                 // col-half 0..1
  const int slot = b * CHUNKS + blockIdx.x;
  const int* __restrict__ idrow = ids + (size_t)b * NN;

  if (tid < CC) lcnt[tid] = 0.f;
  lcid[tid]       = idrow[row0 + tid];
  lcid[tid + 512] = idrow[row0 + tid + 512];
  {
    const float4 z4 = make_float4(0.f, 0.f, 0.f, 0.f);
#pragma unroll
    for (int i = 0; i < 8; ++i)
      *reinterpret_cast<float4*>(&slab[w][(i * 64 + lane) * 4]) = z4;
  }
  __syncthreads();
  atomicAdd(&lcnt[lcid[tid]], 1.f);
  atomicAdd(&lcnt[lcid[tid + 512]], 1.f);

  const float* __restrict__ p0 =
      x + ((size_t)b * NN + row0 + rr * 256) * DD + h * 64 + lane;
  const int kb0 = rr * 256;
  float* const sl = &slab[w][0];

  float vA[8], vB[8];
  int cA[8], cB[8];

#define LOADG(V, C, g)                                                     \
  {                                                                        \
    _Pragma("unroll") for (int k = 0; k < 8; ++k) {                        \
      V[k] = __builtin_nontemporal_load(&p0[((g) * 8 + k) * DD]);          \
      C[k] = lcid[kb0 + (g) * 8 + k];                                      \
    }                                                                      \
  }
#define RMWG(V, C)                                                         \
  {                                                                        \
    _Pragma("unroll") for (int k = 0; k < 8; ++k) {                        \
      float* p = &sl[C[k] * 64 + lane];                                    \
      *p = *p + V[k];                                                      \
    }                                                                      \
  }

  LOADG(vA, cA, 0)                        // 32 groups of 8 rows, ping-pong
#pragma unroll
  for (int i = 0; i < 15; ++i) {
    LOADG(vB, cB, 2 * i + 1)
    RMWG(vA, cA)
    LOADG(vA, cA, 2 * i + 2)
    RMWG(vB, cB)
  }
  LOADG(vB, cB, 31)
  RMWG(vA, cA)                            // group 30
  RMWG(vB, cB)                            // group 31
#undef LOADG
#undef RMWG
  __syncthreads();

  // epilogue: fold 4 row-quarters per col-half, plain-store 16 KB partial
  float* __restrict__ ps = outsums + (size_t)slot * CC * DD;
#pragma unroll
  for (int it = 0; it < 8; ++it) {
    const int idx = it * 512 + tid;       // c*128 + h2*64 + j
    const int c  = idx >> 7;
    const int r  = idx & 127;
    const int h2 = r >> 6;
    const int j  = r & 63;
    const int o  = c * 64 + j;
    ps[idx] = slab[h2][o] + slab[2 + h2][o] + slab[4 + h2][o] + slab[6 + h2][o];
  }
  if (tid < CC) outcnts[slot * CC + tid] = lcnt[tid];
  if (slot == 0 && tid == 0)
    __hip_atomic_store(gctr, 0, __ATOMIC_RELAXED, __HIP_MEMORY_SCOPE_AGENT);
}

// ---------------- Kernel 2: fused reduce + gram + final (R7, proven) --------
#define MSTR 132
__global__ __launch_bounds__(512) void finish_fused_kernel(
    const float* __restrict__ psums, const float* __restrict__ pcnts,
    float* __restrict__ lossp, int* __restrict__ gctr,
    float* __restrict__ out) {
  __shared__ float mean[CC * MSTR];
  __shared__ float cnt[CC];
  __shared__ float red[512];

  const int b = blockIdx.x;
  const int tid = threadIdx.x;

  if (tid < CC) {
    float cs = 0.f;
#pragma unroll
    for (int c = 0; c < CHUNKS; ++c) cs += pcnts[(b * CHUNKS + c) * CC + tid];
    cnt[tid] = cs;
  }

  float4 a0 = make_float4(0.f, 0.f, 0.f, 0.f), a1 = a0;
  const size_t base = (size_t)b * CHUNKS * CC * DD + (size_t)tid * 8;
#pragma unroll 4
  for (int c = 0; c < CHUNKS; ++c) {
    const float4* p = reinterpret_cast<const float4*>(&psums[base + (size_t)c * CC * DD]);
    float4 q0 = p[0], q1 = p[1];
    a0.x += q0.x; a0.y += q0.y; a0.z += q0.z; a0.w += q0.w;
    a1.x += q1.x; a1.y += q1.y; a1.z += q1.z; a1.w += q1.w;
  }
  __syncthreads();

  {
    const int c = tid >> 4;
    const int d0 = (tid & 15) * 8;
    const float inv = 1.f / fmaxf(cnt[c], 1.f);
    float* mrow = &mean[c * MSTR + d0];
    mrow[0] = a0.x * inv; mrow[1] = a0.y * inv; mrow[2] = a0.z * inv; mrow[3] = a0.w * inv;
    mrow[4] = a1.x * inv; mrow[5] = a1.y * inv; mrow[6] = a1.z * inv; mrow[7] = a1.w * inv;
  }
  __syncthreads();

  float acc = 0.f;
  if (tid < (CC * (CC - 1)) / 2) {
    int c = 0, rem = tid;
    while (rem >= (CC - 1 - c)) { rem -= (CC - 1 - c); ++c; }
    int e = c + 1 + rem;
    const float4* mc = reinterpret_cast<const float4*>(&mean[c * MSTR]);
    const float4* me = reinterpret_cast<const float4*>(&mean[e * MSTR]);
    float dot = 0.f;
#pragma unroll 8
    for (int j = 0; j < DD / 4; ++j) {
      float4 u = mc[j], v = me[j];
      dot += u.x * v.x + u.y * v.y + u.z * v.z + u.w * v.w;
    }
    acc = fabsf(dot);
  }

  red[tid] = acc;
  __syncthreads();
  for (int s = 256; s > 0; s >>= 1) {
    if (tid < s) red[tid] += red[tid + s];
    __syncthreads();
  }

  if (tid == 0) {
    float valid = 0.f;
    for (int c = 0; c < CC; ++c) valid += (cnt[c] > 0.f) ? 1.f : 0.f;
    float denom = (valid > 1.f) ? valid * (valid - 1.f) * 0.5f : 1.f;
    float v = red[0] / denom * (1.0f / BB);
    __hip_atomic_store(&lossp[b], v, __ATOMIC_RELAXED, __HIP_MEMORY_SCOPE_AGENT);
    __threadfence();
    int old = __hip_atomic_fetch_add(gctr, 1, __ATOMIC_ACQ_REL,
                                     __HIP_MEMORY_SCOPE_AGENT);
    if (old == BB - 1) {
      __threadfence();
      float s = 0.f;
#pragma unroll
      for (int i = 0; i < BB; ++i)
        s += __hip_atomic_load(&lossp[i], __ATOMIC_RELAXED,
                               __HIP_MEMORY_SCOPE_AGENT);
      out[0] = s;
    }
  }
}

// ---------------- PATH B fallback (atomic accumulate) -----------------------
#define RPB_B 512
#define ROWS_PER_WAVE_B 128
__global__ __launch_bounds__(256) void seg_sum_rmw_b(
    const float* __restrict__ x, const int* __restrict__ ids,
    float* __restrict__ gsums, float* __restrict__ gcounts) {
  __shared__ float lsum[4][CC * DD];
  __shared__ float lcnt[CC];
  __shared__ int   lcid[RPB_B];

  const int tid  = threadIdx.x;
  const int b    = blockIdx.y;
  const int row0 = blockIdx.x * RPB_B;
  const int lane = tid & 63;
  const int w    = tid >> 6;
  const int* __restrict__ idrow = ids + (size_t)b * NN;

  if (tid < CC) lcnt[tid] = 0.f;
  lcid[tid]       = idrow[row0 + tid];
  lcid[tid + 256] = idrow[row0 + tid + 256];
  {
    const float4 z4 = make_float4(0.f, 0.f, 0.f, 0.f);
#pragma unroll
    for (int i = 0; i < 16; ++i)
      *reinterpret_cast<float4*>(&lsum[w][(i * 64 + lane) * 4]) = z4;
  }
  __syncthreads();
  atomicAdd(&lcnt[lcid[tid]], 1.f);
  atomicAdd(&lcnt[lcid[tid + 256]], 1.f);

  const float2* __restrict__ x2 =
      reinterpret_cast<const float2*>(x + (size_t)b * NN * DD);
  const int wbase = w * ROWS_PER_WAVE_B;
  float* const slab = &lsum[w][0];

  for (int g = 0; g < ROWS_PER_WAVE_B / 8; ++g) {
    float2 v[8]; int cid[8];
#pragma unroll
    for (int k = 0; k < 8; ++k) {
      const int rl = wbase + g * 8 + k;
      v[k]   = x2[(size_t)(row0 + rl) * 64 + lane];
      cid[k] = lcid[rl];
    }
#pragma unroll
    for (int k = 0; k < 8; ++k) {
      float2* p = reinterpret_cast<float2*>(&slab[cid[k] * DD + 2 * lane]);
      float2 old = *p;
      *p = make_float2(old.x + v[k].x, old.y + v[k].y);
    }
  }
  __syncthreads();

  float* __restrict__ gs = gsums + (size_t)b * CC * DD;
  for (int i = tid; i < CC * DD; i += 256) {
    float s = lsum[0][i] + lsum[1][i] + lsum[2][i] + lsum[3][i];
    atomicAdd(&gs[i], s);
  }
  if (tid < CC) atomicAdd(&gcounts[b * CC + tid], lcnt[tid]);
}

__global__ __launch_bounds__(512) void finish_kernel_b(
    const float* __restrict__ gsums, const float* __restrict__ gcounts,
    float* __restrict__ out) {
  __shared__ float mean[CC * MSTR];
  __shared__ float cnt[CC];
  __shared__ float red[512];

  const int b = blockIdx.x;
  const int tid = threadIdx.x;

  if (tid < CC) cnt[tid] = gcounts[b * CC + tid];
  __syncthreads();
  for (int i = tid; i < CC * DD; i += 512) {
    int c = i >> 7;
    int d = i & 127;
    mean[c * MSTR + d] = gsums[(size_t)b * CC * DD + i] / fmaxf(cnt[c], 1.f);
  }
  __syncthreads();

  float acc = 0.f;
  if (tid < (CC * (CC - 1)) / 2) {
    int c = 0, rem = tid;
    while (rem >= (CC - 1 - c)) { rem -= (CC - 1 - c); ++c; }
    int e = c + 1 + rem;
    const float4* mc = reinterpret_cast<const float4*>(&mean[c * MSTR]);
    const float4* me = reinterpret_cast<const float4*>(&mean[e * MSTR]);
    float dot = 0.f;
#pragma unroll 8
    for (int jj = 0; jj < DD / 4; ++jj) {
      float4 u = mc[jj], v = me[jj];
      dot += u.x * v.x + u.y * v.y + u.z * v.z + u.w * v.w;
    }
    acc = fabsf(dot);
  }
  red[tid] = acc;
  __syncthreads();
  for (int s = 256; s > 0; s >>= 1) {
    if (tid < s) red[tid] += red[tid + s];
    __syncthreads();
  }
  if (tid == 0) {
    float valid = 0.f;
    for (int c = 0; c < CC; ++c) valid += (cnt[c] > 0.f) ? 1.f : 0.f;
    float denom = (valid > 1.f) ? valid * (valid - 1.f) * 0.5f : 1.f;
    atomicAdd(out, red[0] / denom * (1.0f / BB));
  }
}

extern "C" void kernel_launch(void* const* d_in, const int* in_sizes, int n_in,
                              void* d_out, int out_size, void* d_ws, size_t ws_size,
                              hipStream_t stream) {
  const float* x   = (const float*)d_in[0];
  const int*   ids = (const int*)d_in[1];
  float* out = (float*)d_out;
  float* ws  = (float*)d_ws;

  if (ws_size >= WS_A_FLOATS * sizeof(float)) {
    float* psums = ws + P_SUMS;
    float* pcnts = ws + P_CNTS;
    float* lossp = ws + LOSSP;
    int*   gctr  = (int*)(ws + GCTR);
    dim3 grid1(CHUNKS, BB);
    seg_sum_kernel<<<grid1, 512, 0, stream>>>(x, ids, psums, pcnts, gctr);
    finish_fused_kernel<<<BB, 512, 0, stream>>>(psums, pcnts, lossp, gctr, out);
  } else {
    float* gsums   = ws;
    float* gcounts = gsums + (size_t)BB * CC * DD;
    const size_t wsb = ((size_t)BB * CC * DD + (size_t)BB * CC) * sizeof(float);
    hipMemsetAsync(d_ws, 0, wsb, stream);
    hipMemsetAsync(d_out, 0, sizeof(float), stream);
    dim3 gridb(NN / RPB_B, BB);
    seg_sum_rmw_b<<<gridb, 256, 0, stream>>>(x, ids, gsums, gcounts);
    finish_kernel_b<<<BB, 512, 0, stream>>>(gsums, gcounts, out);
  }
}